// Round 2
// baseline (580.460 us; speedup 1.0000x reference)
//
#include <hip/hip_runtime.h>

#define B_ 8
#define C_ 128
#define L_ 4096
#define P_ 96
#define D_ 16

typedef __attribute__((ext_vector_type(8))) short short8;
typedef __attribute__((ext_vector_type(16))) float float16v;

__device__ __forceinline__ unsigned short f2bf(float f) {
  unsigned int u = __float_as_uint(f);
  u += 0x7fff + ((u >> 16) & 1);          // round-to-nearest-even
  return (unsigned short)(u >> 16);
}

// ---------------------------------------------------------------------------
// Workspace layout (bytes)
// ---------------------------------------------------------------------------
constexpr size_t OFF_H      = 0;                      // h  [B][C][L] f32 : 16 MB
constexpr size_t OFF_PSUM   = 16777216;               // [C][4] f32
constexpr size_t OFF_PSUMSQ = OFF_PSUM + 8192;
constexpr size_t OFF_SCALE  = OFF_PSUMSQ + 8192;      // [C] f32
constexpr size_t OFF_SHIFT  = OFF_SCALE + 512;
constexpr size_t OFF_WALLT  = OFF_SHIFT + 512;        // WallT [c][r] f32 64 KB
constexpr size_t OFF_BALL   = OFF_WALLT + 65536;      // [128] f32
constexpr size_t OFF_QT     = OFF_BALL + 512;         // [B][L][16] bf16 : 1 MB  (pre-scaled by log2e)
constexpr size_t OFF_KT     = OFF_QT + 1048576;       // [B][L][16] bf16 : 1 MB
constexpr size_t OFF_V2     = OFF_KT + 1048576;       // [B][96][L] bf16 : 6 MB

// ---------------------------------------------------------------------------
// k_prep: rows 0..15 = Wq, 16..31 = Wk, 32..127 = Wv2 = W2 @ Wv.
// Stored transposed wallT[c*128+r]. ball = {bq, bk, W2@bv}. bt is annihilated
// by BatchNorm shift-invariance and never read.
// ---------------------------------------------------------------------------
__global__ __launch_bounds__(128) void k_prep(
    const float* __restrict__ Wq, const float* __restrict__ bq,
    const float* __restrict__ Wk, const float* __restrict__ bk,
    const float* __restrict__ Wv, const float* __restrict__ bv,
    const float* __restrict__ W2,
    float* __restrict__ wallT, float* __restrict__ ball)
{
  const int r = blockIdx.x;
  const int c = threadIdx.x;
  float wv;
  if (r < 16) {
    wv = Wq[r * C_ + c];
  } else if (r < 32) {
    wv = Wk[(r - 16) * C_ + c];
  } else {
    const int p = r - 32;
    float s = 0.f;
    for (int o = 0; o < C_; ++o) s += W2[p * C_ + o] * Wv[o * C_ + c];
    wv = s;
  }
  wallT[c * C_ + r] = wv;
  if (c == 0) {
    float bb;
    if (r < 16)      bb = bq[r];
    else if (r < 32) bb = bk[r - 16];
    else {
      const int p = r - 32;
      float s = 0.f;
      for (int o = 0; o < C_; ++o) s += W2[p * C_ + o] * bv[o];
      bb = s;
    }
    ball[r] = bb;
  }
}

// ---------------------------------------------------------------------------
// k_conv: h[b,o,l] = sum_i x[b,i] * Wt[i,o,l].  float4 loads: 1 KB/wave/instr.
// Grid (4 l-tiles x 128 o), 256 thr, 4 l per thread, acc over 8 batches.
// Deterministic per-block BN partials.
// ---------------------------------------------------------------------------
__global__ __launch_bounds__(256) void k_conv(
    const float* __restrict__ x, const float* __restrict__ Wt,
    float* __restrict__ h, float* __restrict__ psum, float* __restrict__ psumsq)
{
  __shared__ float4 xs4[256];                 // [b][i4] = b*32+i4
  __shared__ float rs1[4], rs2[4];
  const int tid = threadIdx.x;
  const int o = blockIdx.y;
  const int l = blockIdx.x * 1024 + tid * 4;

  xs4[tid] = ((const float4*)x)[tid];        // 1024 floats exactly
  __syncthreads();

  float4 acc[8];
#pragma unroll
  for (int bb = 0; bb < 8; ++bb) acc[bb] = (float4){0.f, 0.f, 0.f, 0.f};

  const float* wp = Wt + (size_t)o * L_ + l;
  const size_t stride = (size_t)C_ * L_;
#pragma unroll 2
  for (int i4 = 0; i4 < 32; ++i4) {
    const float4 w0 = *(const float4*)(wp + (size_t)(i4 * 4 + 0) * stride);
    const float4 w1 = *(const float4*)(wp + (size_t)(i4 * 4 + 1) * stride);
    const float4 w2 = *(const float4*)(wp + (size_t)(i4 * 4 + 2) * stride);
    const float4 w3 = *(const float4*)(wp + (size_t)(i4 * 4 + 3) * stride);
#pragma unroll
    for (int bb = 0; bb < 8; ++bb) {
      const float4 xb = xs4[bb * 32 + i4];   // same addr across wave: broadcast
      acc[bb].x += xb.x * w0.x + xb.y * w1.x + xb.z * w2.x + xb.w * w3.x;
      acc[bb].y += xb.x * w0.y + xb.y * w1.y + xb.z * w2.y + xb.w * w3.y;
      acc[bb].z += xb.x * w0.z + xb.y * w1.z + xb.z * w2.z + xb.w * w3.z;
      acc[bb].w += xb.x * w0.w + xb.y * w1.w + xb.z * w2.w + xb.w * w3.w;
    }
  }
  float s1 = 0.f, s2 = 0.f;
#pragma unroll
  for (int bb = 0; bb < 8; ++bb) {
    *(float4*)(h + ((size_t)(bb * C_ + o)) * L_ + l) = acc[bb];
    s1 += acc[bb].x + acc[bb].y + acc[bb].z + acc[bb].w;
    s2 += acc[bb].x * acc[bb].x + acc[bb].y * acc[bb].y
        + acc[bb].z * acc[bb].z + acc[bb].w * acc[bb].w;
  }
  for (int off = 1; off < 64; off <<= 1) {
    s1 += __shfl_xor(s1, off);
    s2 += __shfl_xor(s2, off);
  }
  if ((tid & 63) == 0) { rs1[tid >> 6] = s1; rs2[tid >> 6] = s2; }
  __syncthreads();
  if (tid == 0) {
    psum[o * 4 + blockIdx.x]   = rs1[0] + rs1[1] + rs1[2] + rs1[3];
    psumsq[o * 4 + blockIdx.x] = rs2[0] + rs2[1] + rs2[2] + rs2[3];
  }
}

// ---------------------------------------------------------------------------
// k_bn: finalize per-channel scale/shift.
// ---------------------------------------------------------------------------
__global__ __launch_bounds__(128) void k_bn(
    const float* __restrict__ psum, const float* __restrict__ psumsq,
    const float* __restrict__ gamma, const float* __restrict__ beta,
    float* __restrict__ scale, float* __restrict__ shift)
{
  const int c = threadIdx.x;
  float s1 = 0.f, s2 = 0.f;
  for (int t = 0; t < 4; ++t) { s1 += psum[c * 4 + t]; s2 += psumsq[c * 4 + t]; }
  const float inv = 1.f / 32768.f;
  const float mean = s1 * inv;
  const float var  = s2 * inv - mean * mean;
  const float sc   = rsqrtf(var + 1e-5f) * gamma[c];
  scale[c] = sc;
  shift[c] = beta[c] - mean * sc;
}

// ---------------------------------------------------------------------------
// k_proj: [q;k;v2] = Wall @ relu(bn(h)) + ball, bf16 out.
// q rows pre-scaled by log2e so attention uses raw v_exp_f32 (exp2).
// ---------------------------------------------------------------------------
__global__ __launch_bounds__(256) void k_proj(
    const float* __restrict__ h, const float* __restrict__ scale,
    const float* __restrict__ shift, const float* __restrict__ wallT,
    const float* __restrict__ ball,
    unsigned short* __restrict__ qT, unsigned short* __restrict__ kT,
    unsigned short* __restrict__ v2w)
{
  const int b = blockIdx.y;
  const int l0 = blockIdx.x * 64;
  const int tid = threadIdx.x;
  const int wu = __builtin_amdgcn_readfirstlane(tid) >> 6;  // wave id, uniform
  const int lane = tid & 63;
  const int l = l0 + lane;

  float acc[32];
#pragma unroll
  for (int r = 0; r < 32; ++r) acc[r] = ball[wu * 32 + r];

#pragma unroll 2
  for (int c = 0; c < C_; ++c) {
    const float hv = h[((size_t)(b * C_ + c)) * L_ + l];
    const float hn = fmaxf(hv * scale[c] + shift[c], 0.f);
    const float* wrow = wallT + c * C_ + wu * 32;   // 32 consecutive floats
#pragma unroll
    for (int r = 0; r < 32; ++r) acc[r] += wrow[r] * hn;
  }

  if (wu == 0) {
    const size_t row = (size_t)(b * L_ + l) * D_;
    short8 v0, v1;
#pragma unroll
    for (int r = 0; r < 8; ++r) {
      v0[r] = (short)f2bf(acc[r] * 1.44269504f);        // q * log2(e)
      v1[r] = (short)f2bf(acc[8 + r] * 1.44269504f);
    }
    *(short8*)(qT + row) = v0;  *(short8*)(qT + row + 8) = v1;
#pragma unroll
    for (int r = 0; r < 8; ++r) { v0[r] = (short)f2bf(acc[16 + r]); v1[r] = (short)f2bf(acc[24 + r]); }
    *(short8*)(kT + row) = v0;  *(short8*)(kT + row + 8) = v1;
  } else {
    const int pbase = wu * 32 - 32;
#pragma unroll
    for (int r = 0; r < 32; ++r)
      v2w[((size_t)(b * P_ + pbase + r)) * L_ + l] = f2bf(acc[r]);
  }
}

// ---------------------------------------------------------------------------
// k_attn: transposed flash attention, 32x32x16 bf16 MFMA, K = d = 16 exactly.
//   S^T = K Q^T  (A = K rows m, B = Q^T -> cols l; both direct 16B loads)
//   P   = exp2(S^T) in C/D layout (no max subtraction: logits bounded ~|5|,
//         softmax shift-invariant so result identical)
//   O^T = V^T P^T (A = V^T direct from global; B = P^T built in-register via
//         one half-wave shfl_xor(32) pair per 16-m chunk -> NO LDS, NO
//         barriers in the main loop)
// Block = 1024 thr = 16 waves = 4 q-groups (32 q-rows) x 4 m-slices (1024 m).
// Partial O/lsum combined through LDS ds_add_f32 once at the end.
// ---------------------------------------------------------------------------
__global__ __launch_bounds__(1024, 4) void k_attn(
    const unsigned short* __restrict__ qT, const unsigned short* __restrict__ kT,
    const unsigned short* __restrict__ v2w, const float* __restrict__ b2,
    float* __restrict__ y)
{
  __shared__ float ldsO[P_ * 128];   // [p][l] 48 KB
  __shared__ float ldsL[128];

  const int b = blockIdx.y;
  const int l0 = blockIdx.x * 128;
  const int tid = threadIdx.x;
  const int w  = tid >> 6;
  const int qg = w & 3;          // q-group
  const int ms = w >> 2;         // m-slice
  const int lane = tid & 63;
  const int col = lane & 31;
  const int hh  = lane >> 5;     // half-wave

  // zero the reduction buffers
#pragma unroll
  for (int i = 0; i < 12; ++i) ldsO[tid + i * 1024] = 0.f;
  if (tid < 128) ldsL[tid] = 0.f;
  __syncthreads();

  // Q^T B-fragment: B[k=8*hh+j][n=col], row lq of qT
  const int lq = l0 + qg * 32 + col;
  const short8 qf = *(const short8*)(qT + ((size_t)(b * L_ + lq)) * D_ + hh * 8);

  float16v oacc[3];
#pragma unroll
  for (int pt = 0; pt < 3; ++pt)
#pragma unroll
    for (int r = 0; r < 16; ++r) oacc[pt][r] = 0.f;
  float lsum = 0.f;

  const unsigned short* kbase =
      kT + ((size_t)(b * L_ + ms * 1024 + col)) * D_ + hh * 8;
  const unsigned short* vbb = v2w + (size_t)(b * P_ + col) * L_;

#pragma unroll 1
  for (int it = 0; it < 32; ++it) {
    const short8 kf = *(const short8*)(kbase + (size_t)it * 32 * D_);
    float16v zero;
#pragma unroll
    for (int r = 0; r < 16; ++r) zero[r] = 0.f;
    const float16v s = __builtin_amdgcn_mfma_f32_32x32x16_bf16(kf, qf, zero, 0, 0, 0);

    // P = exp2(S^T); pack bf16 pairs (round-half-up: P > 0 always)
    unsigned dw[8];
#pragma unroll
    for (int g = 0; g < 8; ++g) {
      const float e0 = __builtin_amdgcn_exp2f(s[2 * g]);
      const float e1 = __builtin_amdgcn_exp2f(s[2 * g + 1]);
      lsum += e0 + e1;
      const unsigned u0 = __float_as_uint(e0) + 0x8000u;
      const unsigned u1 = __float_as_uint(e1) + 0x8000u;
      dw[g] = __builtin_amdgcn_perm(u1, u0, 0x07060302u);  // (bf(e1)<<16)|bf(e0)
    }

    const int mbase = ms * 1024 + it * 32;
#pragma unroll
    for (int mt = 0; mt < 2; ++mt) {
      // build P^T B-frag for k = mt*16 + 8*hh + j via half-wave exchange
      const unsigned t0 = hh ? dw[4 * mt + 0] : dw[4 * mt + 2];
      const unsigned t1 = hh ? dw[4 * mt + 1] : dw[4 * mt + 3];
      const unsigned r0 = (unsigned)__shfl_xor((int)t0, 32);
      const unsigned r1 = (unsigned)__shfl_xor((int)t1, 32);
      union { int4 i; short8 s8; } pu;
      pu.i.x = hh ? (int)r0 : (int)dw[4 * mt + 0];
      pu.i.y = hh ? (int)r1 : (int)dw[4 * mt + 1];
      pu.i.z = hh ? (int)dw[4 * mt + 2] : (int)r0;
      pu.i.w = hh ? (int)dw[4 * mt + 3] : (int)r1;
      const short8 pf = pu.s8;

      const size_t moff = (size_t)(mbase + mt * 16 + hh * 8);
#pragma unroll
      for (int pt = 0; pt < 3; ++pt) {
        const short8 vf = *(const short8*)(vbb + (size_t)pt * 32 * L_ + moff);
        oacc[pt] = __builtin_amdgcn_mfma_f32_32x32x16_bf16(vf, pf, oacc[pt], 0, 0, 0);
      }
    }
  }

  // combine partials across m-slices (and half-waves) in LDS
  atomicAdd(&ldsL[qg * 32 + col], lsum);
#pragma unroll
  for (int pt = 0; pt < 3; ++pt)
#pragma unroll
    for (int r = 0; r < 16; ++r) {
      const int p = (r & 3) + 8 * (r >> 2) + 4 * hh + 32 * pt;
      atomicAdd(&ldsO[p * 128 + qg * 32 + col], oacc[pt][r]);
    }
  __syncthreads();

  // y[b,p,l0+l] = O^T[p][l]/lsum[l] + b2[p]
#pragma unroll
  for (int i = 0; i < 12; ++i) {
    const int idx = tid + i * 1024;
    const int p = idx >> 7;
    const int l = idx & 127;
    y[((size_t)(b * P_ + p)) * L_ + l0 + l] = ldsO[idx] / ldsL[l] + b2[p];
  }
}

// ---------------------------------------------------------------------------
extern "C" void kernel_launch(void* const* d_in, const int* in_sizes, int n_in,
                              void* d_out, int out_size, void* d_ws, size_t ws_size,
                              hipStream_t stream) {
  (void)in_sizes; (void)n_in; (void)out_size; (void)ws_size;
  const float* x     = (const float*)d_in[0];
  const float* Wt    = (const float*)d_in[1];
  // d_in[2] = bt: unused — BatchNorm mean-subtraction cancels it exactly.
  const float* gamma = (const float*)d_in[3];
  const float* beta  = (const float*)d_in[4];
  const float* Wq    = (const float*)d_in[5];
  const float* bq    = (const float*)d_in[6];
  const float* Wk    = (const float*)d_in[7];
  const float* bk    = (const float*)d_in[8];
  const float* Wv    = (const float*)d_in[9];
  const float* bv    = (const float*)d_in[10];
  const float* W2    = (const float*)d_in[11];
  const float* b2    = (const float*)d_in[12];
  float* y = (float*)d_out;

  char* ws = (char*)d_ws;
  float* h       = (float*)(ws + OFF_H);
  float* psum    = (float*)(ws + OFF_PSUM);
  float* psumsq  = (float*)(ws + OFF_PSUMSQ);
  float* scale   = (float*)(ws + OFF_SCALE);
  float* shift   = (float*)(ws + OFF_SHIFT);
  float* wallT   = (float*)(ws + OFF_WALLT);
  float* ball    = (float*)(ws + OFF_BALL);
  unsigned short* qT  = (unsigned short*)(ws + OFF_QT);
  unsigned short* kT  = (unsigned short*)(ws + OFF_KT);
  unsigned short* v2w = (unsigned short*)(ws + OFF_V2);

  k_prep<<<128, 128, 0, stream>>>(Wq, bq, Wk, bk, Wv, bv, W2, wallT, ball);
  k_conv<<<dim3(4, 128), 256, 0, stream>>>(x, Wt, h, psum, psumsq);
  k_bn<<<1, 128, 0, stream>>>(psum, psumsq, gamma, beta, scale, shift);
  k_proj<<<dim3(64, 8), 256, 0, stream>>>(h, scale, shift, wallT, ball, qT, kT, v2w);
  k_attn<<<dim3(32, 8), 1024, 0, stream>>>(qT, kT, v2w, b2, y);
}

// Round 3
// 577.936 us; speedup vs baseline: 1.0044x; 1.0044x over previous
//
#include <hip/hip_runtime.h>

#define B_ 8
#define C_ 128
#define L_ 4096
#define P_ 96
#define D_ 16

typedef __attribute__((ext_vector_type(8))) short short8;
typedef __attribute__((ext_vector_type(16))) float float16v;

__device__ __forceinline__ unsigned short f2bf(float f) {
  unsigned int u = __float_as_uint(f);
  u += 0x7fff + ((u >> 16) & 1);          // round-to-nearest-even
  return (unsigned short)(u >> 16);
}

// ---------------------------------------------------------------------------
// Workspace layout (bytes)
// ---------------------------------------------------------------------------
constexpr size_t OFF_H      = 0;                      // h  [B][C][L] f32 : 16 MB
constexpr size_t OFF_PSUM   = 16777216;               // [C][4] f32
constexpr size_t OFF_PSUMSQ = OFF_PSUM + 8192;
constexpr size_t OFF_SCALE  = OFF_PSUMSQ + 8192;      // [C] f32
constexpr size_t OFF_SHIFT  = OFF_SCALE + 512;
constexpr size_t OFF_WALLT  = OFF_SHIFT + 512;        // WallT [c][r] f32 64 KB
constexpr size_t OFF_BALL   = OFF_WALLT + 65536;      // [128] f32
constexpr size_t OFF_QT     = OFF_BALL + 512;         // [B][L][16] bf16 (q pre-scaled by log2e)
constexpr size_t OFF_KT     = OFF_QT + 1048576;       // [B][L][16] bf16
constexpr size_t OFF_V2     = OFF_KT + 1048576;       // [B][96][L] bf16 : 6 MB

// ---------------------------------------------------------------------------
// k_prep: rows 0..15 = Wq, 16..31 = Wk, 32..127 = Wv2 = W2 @ Wv.
// Stored transposed wallT[c*128+r]. ball = {bq, bk, W2@bv}. bt is annihilated
// by BatchNorm shift-invariance and never read.
// ---------------------------------------------------------------------------
__global__ __launch_bounds__(128) void k_prep(
    const float* __restrict__ Wq, const float* __restrict__ bq,
    const float* __restrict__ Wk, const float* __restrict__ bk,
    const float* __restrict__ Wv, const float* __restrict__ bv,
    const float* __restrict__ W2,
    float* __restrict__ wallT, float* __restrict__ ball)
{
  const int r = blockIdx.x;
  const int c = threadIdx.x;
  float wv;
  if (r < 16) {
    wv = Wq[r * C_ + c];
  } else if (r < 32) {
    wv = Wk[(r - 16) * C_ + c];
  } else {
    const int p = r - 32;
    float s = 0.f;
#pragma unroll 8
    for (int o = 0; o < C_; ++o) s += W2[p * C_ + o] * Wv[o * C_ + c];
    wv = s;
  }
  wallT[c * C_ + r] = wv;
  if (c == 0) {
    float bb;
    if (r < 16)      bb = bq[r];
    else if (r < 32) bb = bk[r - 16];
    else {
      const int p = r - 32;
      float s = 0.f;
#pragma unroll 8
      for (int o = 0; o < C_; ++o) s += W2[p * C_ + o] * bv[o];
      bb = s;
    }
    ball[r] = bb;
  }
}

// ---------------------------------------------------------------------------
// k_conv: h[b,o,l] = sum_i x[b,i] * Wt[i,o,l].
// Explicit double-buffered float4 loads (8 in flight) hide HBM latency;
// per-block phase rotation of the i-order decorrelates the 2 MB power-of-2
// stride across concurrently-running blocks (HBM channel spread).
// Deterministic per-block BN partials (no atomics).
// ---------------------------------------------------------------------------
__global__ __launch_bounds__(256) void k_conv(
    const float* __restrict__ x, const float* __restrict__ Wt,
    float* __restrict__ h, float* __restrict__ psum, float* __restrict__ psumsq)
{
  __shared__ float4 xs4[256];                 // [b][i4] = b*32+i4
  __shared__ float rs1[4], rs2[4];
  const int tid = threadIdx.x;
  const int o = blockIdx.y;
  const int l = blockIdx.x * 1024 + tid * 4;

  xs4[tid] = ((const float4*)x)[tid];        // 1024 floats exactly
  __syncthreads();

  float4 acc[8];
#pragma unroll
  for (int bb = 0; bb < 8; ++bb) acc[bb] = (float4){0.f, 0.f, 0.f, 0.f};

  const float* wp = Wt + (size_t)o * L_ + l;
  const size_t stride = (size_t)C_ * L_;
  const int phase = (blockIdx.y + blockIdx.x * 8) & 31;

  float4 wbuf[2][4];
#pragma unroll
  for (int q = 0; q < 4; ++q)
    wbuf[0][q] = *(const float4*)(wp + (size_t)(phase * 4 + q) * stride);

#pragma unroll 2
  for (int g = 0; g < 32; ++g) {
    const int cur = g & 1, nb = cur ^ 1;
    const int in4 = ((phase + g + 1) & 31) * 4;   // wraps: always valid
#pragma unroll
    for (int q = 0; q < 4; ++q)
      wbuf[nb][q] = *(const float4*)(wp + (size_t)(in4 + q) * stride);

    const int ic = (phase + g) & 31;
#pragma unroll
    for (int bb = 0; bb < 8; ++bb) {
      const float4 xb = xs4[bb * 32 + ic];   // wave-uniform addr: broadcast
      acc[bb].x += xb.x * wbuf[cur][0].x + xb.y * wbuf[cur][1].x + xb.z * wbuf[cur][2].x + xb.w * wbuf[cur][3].x;
      acc[bb].y += xb.x * wbuf[cur][0].y + xb.y * wbuf[cur][1].y + xb.z * wbuf[cur][2].y + xb.w * wbuf[cur][3].y;
      acc[bb].z += xb.x * wbuf[cur][0].z + xb.y * wbuf[cur][1].z + xb.z * wbuf[cur][2].z + xb.w * wbuf[cur][3].z;
      acc[bb].w += xb.x * wbuf[cur][0].w + xb.y * wbuf[cur][1].w + xb.z * wbuf[cur][2].w + xb.w * wbuf[cur][3].w;
    }
  }
  float s1 = 0.f, s2 = 0.f;
#pragma unroll
  for (int bb = 0; bb < 8; ++bb) {
    *(float4*)(h + ((size_t)(bb * C_ + o)) * L_ + l) = acc[bb];
    s1 += acc[bb].x + acc[bb].y + acc[bb].z + acc[bb].w;
    s2 += acc[bb].x * acc[bb].x + acc[bb].y * acc[bb].y
        + acc[bb].z * acc[bb].z + acc[bb].w * acc[bb].w;
  }
  for (int off = 1; off < 64; off <<= 1) {
    s1 += __shfl_xor(s1, off);
    s2 += __shfl_xor(s2, off);
  }
  if ((tid & 63) == 0) { rs1[tid >> 6] = s1; rs2[tid >> 6] = s2; }
  __syncthreads();
  if (tid == 0) {
    psum[o * 4 + blockIdx.x]   = rs1[0] + rs1[1] + rs1[2] + rs1[3];
    psumsq[o * 4 + blockIdx.x] = rs2[0] + rs2[1] + rs2[2] + rs2[3];
  }
}

// ---------------------------------------------------------------------------
// k_bn: finalize per-channel scale/shift.
// ---------------------------------------------------------------------------
__global__ __launch_bounds__(128) void k_bn(
    const float* __restrict__ psum, const float* __restrict__ psumsq,
    const float* __restrict__ gamma, const float* __restrict__ beta,
    float* __restrict__ scale, float* __restrict__ shift)
{
  const int c = threadIdx.x;
  float s1 = 0.f, s2 = 0.f;
  for (int t = 0; t < 4; ++t) { s1 += psum[c * 4 + t]; s2 += psumsq[c * 4 + t]; }
  const float inv = 1.f / 32768.f;
  const float mean = s1 * inv;
  const float var  = s2 * inv - mean * mean;
  const float sc   = rsqrtf(var + 1e-5f) * gamma[c];
  scale[c] = sc;
  shift[c] = beta[c] - mean * sc;
}

// ---------------------------------------------------------------------------
// k_proj: [q;k;v2] = Wall @ relu(bn(h)) + ball, bf16 out.
// h tile staged ONCE per block into LDS (coalesced float4, bn+relu applied
// during staging); compute loop reads LDS (conflict-free, no global latency).
// v2 stores bounce through LDS -> coalesced 8B global writes.
// q rows pre-scaled by log2e so attention uses raw v_exp_f32 (exp2).
// ---------------------------------------------------------------------------
__global__ __launch_bounds__(256) void k_proj(
    const float* __restrict__ h, const float* __restrict__ scale,
    const float* __restrict__ shift, const float* __restrict__ wallT,
    const float* __restrict__ ball,
    unsigned short* __restrict__ qT, unsigned short* __restrict__ kT,
    unsigned short* __restrict__ v2w)
{
  __shared__ __align__(16) char sm[128 * 68 * 4];     // 34 KB
  float* hn = (float*)sm;                             // [c][68] f32, 64 used
  unsigned short* v2s = (unsigned short*)sm;          // reused: [p][72] bf16

  const int b = blockIdx.y;
  const int l0 = blockIdx.x * 64;
  const int tid = threadIdx.x;

  // stage + bn + relu: 128c x 64l tile
#pragma unroll
  for (int i = 0; i < 8; ++i) {
    const int idx = tid + i * 256;
    const int c = idx >> 4, lq = (idx & 15) * 4;
    const float4 hv = *(const float4*)(h + ((size_t)(b * C_ + c)) * L_ + l0 + lq);
    const float sc = scale[c], sh = shift[c];
    float4 r;
    r.x = fmaxf(hv.x * sc + sh, 0.f);
    r.y = fmaxf(hv.y * sc + sh, 0.f);
    r.z = fmaxf(hv.z * sc + sh, 0.f);
    r.w = fmaxf(hv.w * sc + sh, 0.f);
    *(float4*)(hn + c * 68 + lq) = r;
  }
  __syncthreads();

  const int wu = __builtin_amdgcn_readfirstlane(tid) >> 6;  // wave id, uniform
  const int lane = tid & 63;
  const int l = l0 + lane;

  float acc[32];
#pragma unroll
  for (int r = 0; r < 32; ++r) acc[r] = ball[wu * 32 + r];

#pragma unroll 4
  for (int c = 0; c < C_; ++c) {
    const float hv = hn[c * 68 + lane];
    const float* wrow = wallT + c * C_ + wu * 32;   // wave-uniform: s_load
#pragma unroll
    for (int r = 0; r < 32; ++r) acc[r] += wrow[r] * hv;
  }
  __syncthreads();   // all waves done reading hn before LDS reuse

  if (wu == 0) {
    const size_t row = (size_t)(b * L_ + l) * D_;
    short8 v0, v1;
#pragma unroll
    for (int r = 0; r < 8; ++r) {
      v0[r] = (short)f2bf(acc[r] * 1.44269504f);        // q * log2(e)
      v1[r] = (short)f2bf(acc[8 + r] * 1.44269504f);
    }
    *(short8*)(qT + row) = v0;  *(short8*)(qT + row + 8) = v1;
#pragma unroll
    for (int r = 0; r < 8; ++r) { v0[r] = (short)f2bf(acc[16 + r]); v1[r] = (short)f2bf(acc[24 + r]); }
    *(short8*)(kT + row) = v0;  *(short8*)(kT + row + 8) = v1;
  } else {
    const int pbase = wu * 32 - 32;
#pragma unroll
    for (int r = 0; r < 32; ++r)
      v2s[(pbase + r) * 72 + lane] = f2bf(acc[r]);
  }
  __syncthreads();

  // coalesced v2 stores: 96 rows x 64 l, 8B per thread-chunk
#pragma unroll
  for (int i = 0; i < 6; ++i) {
    const int idx = tid + i * 256;                 // 0..1535
    const int p = idx >> 4, off = (idx & 15) * 4;
    const uint2 val = *(const uint2*)(v2s + p * 72 + off);
    *(uint2*)(v2w + ((size_t)(b * P_ + p)) * L_ + l0 + off) = val;
  }
}

// ---------------------------------------------------------------------------
// k_attn: transposed flash attention, 32x32x16 bf16 MFMA, K = d = 16 exactly.
//   S^T = K Q^T ; P = exp2(S^T) (no max subtraction: logits bounded, softmax
//   shift-invariant) ; O^T = V^T P^T with P^T built in-register via one
//   half-wave shfl_xor(32) pair per 16-m chunk. No LDS in the main loop.
// Software pipeline: K-frag prefetched one iteration ahead (S-chain head);
// V-frags issued at iteration top so the ~300cyc exp chain hides their L2
// latency. Single-buffered V keeps VGPR <= 128 (4 waves/SIMD).
// Block = 1024 thr = 16 waves = 4 q-groups (32 q-rows) x 4 m-slices (1024 m).
// ---------------------------------------------------------------------------
__global__ __launch_bounds__(1024, 4) void k_attn(
    const unsigned short* __restrict__ qT, const unsigned short* __restrict__ kT,
    const unsigned short* __restrict__ v2w, const float* __restrict__ b2,
    float* __restrict__ y)
{
  __shared__ float ldsO[P_ * 128];   // [p][l] 48 KB
  __shared__ float ldsL[128];

  const int b = blockIdx.y;
  const int l0 = blockIdx.x * 128;
  const int tid = threadIdx.x;
  const int w  = tid >> 6;
  const int qg = w & 3;          // q-group
  const int ms = w >> 2;         // m-slice
  const int lane = tid & 63;
  const int col = lane & 31;
  const int hh  = lane >> 5;     // half-wave

#pragma unroll
  for (int i = 0; i < 12; ++i) ldsO[tid + i * 1024] = 0.f;
  if (tid < 128) ldsL[tid] = 0.f;
  __syncthreads();

  // Q^T B-fragment: B[k=8*hh+j][n=col], row lq of qT
  const int lq = l0 + qg * 32 + col;
  const short8 qf = *(const short8*)(qT + ((size_t)(b * L_ + lq)) * D_ + hh * 8);

  float16v oacc[3];
#pragma unroll
  for (int pt = 0; pt < 3; ++pt)
#pragma unroll
    for (int r = 0; r < 16; ++r) oacc[pt][r] = 0.f;
  float lsum = 0.f;

  const unsigned short* kbase =
      kT + ((size_t)(b * L_ + ms * 1024 + col)) * D_ + hh * 8;
  const unsigned short* vbb = v2w + (size_t)(b * P_ + col) * L_;

  short8 kf_cur = *(const short8*)(kbase);

#pragma unroll 2
  for (int it = 0; it < 32; ++it) {
    // prefetch next K-frag (head of the S dependency chain)
    const int itn = (it + 1) & 31;                 // wrap: always valid
    const short8 kf_nxt = *(const short8*)(kbase + (size_t)itn * 32 * D_);

    // issue this iteration's V-frags now; exp chain below hides their latency
    const int mbase = ms * 1024 + it * 32;
    short8 vf[6];
#pragma unroll
    for (int mt = 0; mt < 2; ++mt)
#pragma unroll
      for (int pt = 0; pt < 3; ++pt)
        vf[mt * 3 + pt] = *(const short8*)(vbb + (size_t)pt * 32 * L_
                                           + (size_t)(mbase + mt * 16 + hh * 8));

    float16v zero;
#pragma unroll
    for (int r = 0; r < 16; ++r) zero[r] = 0.f;
    const float16v s = __builtin_amdgcn_mfma_f32_32x32x16_bf16(kf_cur, qf, zero, 0, 0, 0);

    // P = exp2(S^T); pack bf16 pairs
    unsigned dw[8];
#pragma unroll
    for (int g = 0; g < 8; ++g) {
      const float e0 = __builtin_amdgcn_exp2f(s[2 * g]);
      const float e1 = __builtin_amdgcn_exp2f(s[2 * g + 1]);
      lsum += e0 + e1;
#if __has_builtin(__builtin_amdgcn_cvt_pk_bf16_f32)
      typedef __attribute__((ext_vector_type(2))) __bf16 bf162;
      const bf162 pk = __builtin_amdgcn_cvt_pk_bf16_f32(e0, e1);
      dw[g] = *(const unsigned*)&pk;
#else
      const unsigned u0 = __float_as_uint(e0) + 0x8000u;
      const unsigned u1 = __float_as_uint(e1) + 0x8000u;
      dw[g] = __builtin_amdgcn_perm(u1, u0, 0x07060302u);  // (bf(e1)<<16)|bf(e0)
#endif
    }

#pragma unroll
    for (int mt = 0; mt < 2; ++mt) {
      // build P^T B-frag for k = mt*16 + 8*hh + j via half-wave exchange
      const unsigned t0 = hh ? dw[4 * mt + 0] : dw[4 * mt + 2];
      const unsigned t1 = hh ? dw[4 * mt + 1] : dw[4 * mt + 3];
      const unsigned r0 = (unsigned)__shfl_xor((int)t0, 32);
      const unsigned r1 = (unsigned)__shfl_xor((int)t1, 32);
      union { int4 i; short8 s8; } pu;
      pu.i.x = hh ? (int)r0 : (int)dw[4 * mt + 0];
      pu.i.y = hh ? (int)r1 : (int)dw[4 * mt + 1];
      pu.i.z = hh ? (int)dw[4 * mt + 2] : (int)r0;
      pu.i.w = hh ? (int)dw[4 * mt + 3] : (int)r1;
      const short8 pf = pu.s8;
#pragma unroll
      for (int pt = 0; pt < 3; ++pt)
        oacc[pt] = __builtin_amdgcn_mfma_f32_32x32x16_bf16(vf[mt * 3 + pt], pf, oacc[pt], 0, 0, 0);
    }
    kf_cur = kf_nxt;
  }

  // combine partials across m-slices (and half-waves) in LDS
  atomicAdd(&ldsL[qg * 32 + col], lsum);
#pragma unroll
  for (int pt = 0; pt < 3; ++pt)
#pragma unroll
    for (int r = 0; r < 16; ++r) {
      const int p = (r & 3) + 8 * (r >> 2) + 4 * hh + 32 * pt;
      atomicAdd(&ldsO[p * 128 + qg * 32 + col], oacc[pt][r]);
    }
  __syncthreads();

  // y[b,p,l0+l] = O^T[p][l]/lsum[l] + b2[p]
#pragma unroll
  for (int i = 0; i < 12; ++i) {
    const int idx = tid + i * 1024;
    const int p = idx >> 7;
    const int l = idx & 127;
    y[((size_t)(b * P_ + p)) * L_ + l0 + l] = ldsO[idx] / ldsL[l] + b2[p];
  }
}

// ---------------------------------------------------------------------------
extern "C" void kernel_launch(void* const* d_in, const int* in_sizes, int n_in,
                              void* d_out, int out_size, void* d_ws, size_t ws_size,
                              hipStream_t stream) {
  (void)in_sizes; (void)n_in; (void)out_size; (void)ws_size;
  const float* x     = (const float*)d_in[0];
  const float* Wt    = (const float*)d_in[1];
  // d_in[2] = bt: unused — BatchNorm mean-subtraction cancels it exactly.
  const float* gamma = (const float*)d_in[3];
  const float* beta  = (const float*)d_in[4];
  const float* Wq    = (const float*)d_in[5];
  const float* bq    = (const float*)d_in[6];
  const float* Wk    = (const float*)d_in[7];
  const float* bk    = (const float*)d_in[8];
  const float* Wv    = (const float*)d_in[9];
  const float* bv    = (const float*)d_in[10];
  const float* W2    = (const float*)d_in[11];
  const float* b2    = (const float*)d_in[12];
  float* y = (float*)d_out;

  char* ws = (char*)d_ws;
  float* h       = (float*)(ws + OFF_H);
  float* psum    = (float*)(ws + OFF_PSUM);
  float* psumsq  = (float*)(ws + OFF_PSUMSQ);
  float* scale   = (float*)(ws + OFF_SCALE);
  float* shift   = (float*)(ws + OFF_SHIFT);
  float* wallT   = (float*)(ws + OFF_WALLT);
  float* ball    = (float*)(ws + OFF_BALL);
  unsigned short* qT  = (unsigned short*)(ws + OFF_QT);
  unsigned short* kT  = (unsigned short*)(ws + OFF_KT);
  unsigned short* v2w = (unsigned short*)(ws + OFF_V2);

  k_prep<<<128, 128, 0, stream>>>(Wq, bq, Wk, bk, Wv, bv, W2, wallT, ball);
  k_conv<<<dim3(4, 128), 256, 0, stream>>>(x, Wt, h, psum, psumsq);
  k_bn<<<1, 128, 0, stream>>>(psum, psumsq, gamma, beta, scale, shift);
  k_proj<<<dim3(64, 8), 256, 0, stream>>>(h, scale, shift, wallT, ball, qT, kT, v2w);
  k_attn<<<dim3(32, 8), 1024, 0, stream>>>(qT, kT, v2w, b2, y);
}

// Round 4
// 576.772 us; speedup vs baseline: 1.0064x; 1.0020x over previous
//
#include <hip/hip_runtime.h>

#define B_ 8
#define C_ 128
#define L_ 4096
#define P_ 96
#define D_ 16
#define VP 4224   // V row pitch (elements): 8448 B = 256*33 -> row n hits L2
                  // channel (n*33)%32 = n%32: one 32-row strided load spreads
                  // across ALL 32 channels (4096's 8192 B pitch aliased to ONE)

typedef __attribute__((ext_vector_type(8))) short short8;
typedef __attribute__((ext_vector_type(16))) float float16v;

__device__ __forceinline__ unsigned short f2bf(float f) {
  unsigned int u = __float_as_uint(f);
  u += 0x7fff + ((u >> 16) & 1);          // round-to-nearest-even
  return (unsigned short)(u >> 16);
}

// ---------------------------------------------------------------------------
// Workspace layout (bytes)
// ---------------------------------------------------------------------------
constexpr size_t OFF_H      = 0;                      // h  [B][C][L] f32 : 16 MB
constexpr size_t OFF_PSUM   = 16777216;               // [C][4] f32
constexpr size_t OFF_PSUMSQ = OFF_PSUM + 8192;
constexpr size_t OFF_SCALE  = OFF_PSUMSQ + 8192;      // [C] f32
constexpr size_t OFF_SHIFT  = OFF_SCALE + 512;
constexpr size_t OFF_WALLT  = OFF_SHIFT + 512;        // WallT [c][r] f32 64 KB
constexpr size_t OFF_BALL   = OFF_WALLT + 65536;      // [128] f32
constexpr size_t OFF_QT     = OFF_BALL + 512;         // [B][L][16] bf16 (q pre-scaled by log2e)
constexpr size_t OFF_KT     = OFF_QT + 1048576;       // [B][L][16] bf16
constexpr size_t OFF_V2     = OFF_KT + 1048576;       // [B][96][VP] bf16 : 6.5 MB

// ---------------------------------------------------------------------------
// k_prep: rows 0..15 = Wq, 16..31 = Wk, 32..127 = Wv2 = W2 @ Wv.
// Stored transposed wallT[c*128+r]. ball = {bq, bk, W2@bv}. bt is annihilated
// by BatchNorm shift-invariance and never read.
// ---------------------------------------------------------------------------
__global__ __launch_bounds__(128) void k_prep(
    const float* __restrict__ Wq, const float* __restrict__ bq,
    const float* __restrict__ Wk, const float* __restrict__ bk,
    const float* __restrict__ Wv, const float* __restrict__ bv,
    const float* __restrict__ W2,
    float* __restrict__ wallT, float* __restrict__ ball)
{
  const int r = blockIdx.x;
  const int c = threadIdx.x;
  float wv;
  if (r < 16) {
    wv = Wq[r * C_ + c];
  } else if (r < 32) {
    wv = Wk[(r - 16) * C_ + c];
  } else {
    const int p = r - 32;
    float s = 0.f;
#pragma unroll 8
    for (int o = 0; o < C_; ++o) s += W2[p * C_ + o] * Wv[o * C_ + c];
    wv = s;
  }
  wallT[c * C_ + r] = wv;
  if (c == 0) {
    float bb;
    if (r < 16)      bb = bq[r];
    else if (r < 32) bb = bk[r - 16];
    else {
      const int p = r - 32;
      float s = 0.f;
#pragma unroll 8
      for (int o = 0; o < C_; ++o) s += W2[p * C_ + o] * bv[o];
      bb = s;
    }
    ball[r] = bb;
  }
}

// ---------------------------------------------------------------------------
// k_conv: h[b,o,l] = sum_i x[b,i] * Wt[i,o,l].
// Double-buffered float4 loads (8 in flight); per-block phase rotation of the
// i-order decorrelates the 2 MB stride across blocks. Deterministic BN partials.
// ---------------------------------------------------------------------------
__global__ __launch_bounds__(256) void k_conv(
    const float* __restrict__ x, const float* __restrict__ Wt,
    float* __restrict__ h, float* __restrict__ psum, float* __restrict__ psumsq)
{
  __shared__ float4 xs4[256];                 // [b][i4] = b*32+i4
  __shared__ float rs1[4], rs2[4];
  const int tid = threadIdx.x;
  const int o = blockIdx.y;
  const int l = blockIdx.x * 1024 + tid * 4;

  xs4[tid] = ((const float4*)x)[tid];        // 1024 floats exactly
  __syncthreads();

  float4 acc[8];
#pragma unroll
  for (int bb = 0; bb < 8; ++bb) acc[bb] = (float4){0.f, 0.f, 0.f, 0.f};

  const float* wp = Wt + (size_t)o * L_ + l;
  const size_t stride = (size_t)C_ * L_;
  const int phase = (blockIdx.y + blockIdx.x * 8) & 31;

  float4 wbuf[2][4];
#pragma unroll
  for (int q = 0; q < 4; ++q)
    wbuf[0][q] = *(const float4*)(wp + (size_t)(phase * 4 + q) * stride);

#pragma unroll 2
  for (int g = 0; g < 32; ++g) {
    const int cur = g & 1, nb = cur ^ 1;
    const int in4 = ((phase + g + 1) & 31) * 4;   // wraps: always valid
#pragma unroll
    for (int q = 0; q < 4; ++q)
      wbuf[nb][q] = *(const float4*)(wp + (size_t)(in4 + q) * stride);

    const int ic = (phase + g) & 31;
#pragma unroll
    for (int bb = 0; bb < 8; ++bb) {
      const float4 xb = xs4[bb * 32 + ic];   // wave-uniform addr: broadcast
      acc[bb].x += xb.x * wbuf[cur][0].x + xb.y * wbuf[cur][1].x + xb.z * wbuf[cur][2].x + xb.w * wbuf[cur][3].x;
      acc[bb].y += xb.x * wbuf[cur][0].y + xb.y * wbuf[cur][1].y + xb.z * wbuf[cur][2].y + xb.w * wbuf[cur][3].y;
      acc[bb].z += xb.x * wbuf[cur][0].z + xb.y * wbuf[cur][1].z + xb.z * wbuf[cur][2].z + xb.w * wbuf[cur][3].z;
      acc[bb].w += xb.x * wbuf[cur][0].w + xb.y * wbuf[cur][1].w + xb.z * wbuf[cur][2].w + xb.w * wbuf[cur][3].w;
    }
  }
  float s1 = 0.f, s2 = 0.f;
#pragma unroll
  for (int bb = 0; bb < 8; ++bb) {
    *(float4*)(h + ((size_t)(bb * C_ + o)) * L_ + l) = acc[bb];
    s1 += acc[bb].x + acc[bb].y + acc[bb].z + acc[bb].w;
    s2 += acc[bb].x * acc[bb].x + acc[bb].y * acc[bb].y
        + acc[bb].z * acc[bb].z + acc[bb].w * acc[bb].w;
  }
  for (int off = 1; off < 64; off <<= 1) {
    s1 += __shfl_xor(s1, off);
    s2 += __shfl_xor(s2, off);
  }
  if ((tid & 63) == 0) { rs1[tid >> 6] = s1; rs2[tid >> 6] = s2; }
  __syncthreads();
  if (tid == 0) {
    psum[o * 4 + blockIdx.x]   = rs1[0] + rs1[1] + rs1[2] + rs1[3];
    psumsq[o * 4 + blockIdx.x] = rs2[0] + rs2[1] + rs2[2] + rs2[3];
  }
}

// ---------------------------------------------------------------------------
// k_bn: finalize per-channel scale/shift.
// ---------------------------------------------------------------------------
__global__ __launch_bounds__(128) void k_bn(
    const float* __restrict__ psum, const float* __restrict__ psumsq,
    const float* __restrict__ gamma, const float* __restrict__ beta,
    float* __restrict__ scale, float* __restrict__ shift)
{
  const int c = threadIdx.x;
  float s1 = 0.f, s2 = 0.f;
  for (int t = 0; t < 4; ++t) { s1 += psum[c * 4 + t]; s2 += psumsq[c * 4 + t]; }
  const float inv = 1.f / 32768.f;
  const float mean = s1 * inv;
  const float var  = s2 * inv - mean * mean;
  const float sc   = rsqrtf(var + 1e-5f) * gamma[c];
  scale[c] = sc;
  shift[c] = beta[c] - mean * sc;
}

// ---------------------------------------------------------------------------
// k_proj: [q;k;v2] = Wall @ relu(bn(h)) + ball, bf16 out.
// h tile staged once into LDS (bn+relu applied); v2 stores bounce through LDS
// for coalesced 8B writes at the PADDED pitch VP.
// q rows pre-scaled by log2e so attention uses raw v_exp_f32 (exp2).
// ---------------------------------------------------------------------------
__global__ __launch_bounds__(256) void k_proj(
    const float* __restrict__ h, const float* __restrict__ scale,
    const float* __restrict__ shift, const float* __restrict__ wallT,
    const float* __restrict__ ball,
    unsigned short* __restrict__ qT, unsigned short* __restrict__ kT,
    unsigned short* __restrict__ v2w)
{
  __shared__ __align__(16) char sm[128 * 68 * 4];     // 34 KB
  float* hn = (float*)sm;                             // [c][68] f32, 64 used
  unsigned short* v2s = (unsigned short*)sm;          // reused: [p][72] bf16

  const int b = blockIdx.y;
  const int l0 = blockIdx.x * 64;
  const int tid = threadIdx.x;

  // stage + bn + relu: 128c x 64l tile
#pragma unroll
  for (int i = 0; i < 8; ++i) {
    const int idx = tid + i * 256;
    const int c = idx >> 4, lq = (idx & 15) * 4;
    const float4 hv = *(const float4*)(h + ((size_t)(b * C_ + c)) * L_ + l0 + lq);
    const float sc = scale[c], sh = shift[c];
    float4 r;
    r.x = fmaxf(hv.x * sc + sh, 0.f);
    r.y = fmaxf(hv.y * sc + sh, 0.f);
    r.z = fmaxf(hv.z * sc + sh, 0.f);
    r.w = fmaxf(hv.w * sc + sh, 0.f);
    *(float4*)(hn + c * 68 + lq) = r;
  }
  __syncthreads();

  const int wu = __builtin_amdgcn_readfirstlane(tid) >> 6;  // wave id, uniform
  const int lane = tid & 63;
  const int l = l0 + lane;

  float acc[32];
#pragma unroll
  for (int r = 0; r < 32; ++r) acc[r] = ball[wu * 32 + r];

#pragma unroll 4
  for (int c = 0; c < C_; ++c) {
    const float hv = hn[c * 68 + lane];
    const float* wrow = wallT + c * C_ + wu * 32;   // wave-uniform: s_load
#pragma unroll
    for (int r = 0; r < 32; ++r) acc[r] += wrow[r] * hv;
  }
  __syncthreads();   // all waves done reading hn before LDS reuse

  if (wu == 0) {
    const size_t row = (size_t)(b * L_ + l) * D_;
    short8 v0, v1;
#pragma unroll
    for (int r = 0; r < 8; ++r) {
      v0[r] = (short)f2bf(acc[r] * 1.44269504f);        // q * log2(e)
      v1[r] = (short)f2bf(acc[8 + r] * 1.44269504f);
    }
    *(short8*)(qT + row) = v0;  *(short8*)(qT + row + 8) = v1;
#pragma unroll
    for (int r = 0; r < 8; ++r) { v0[r] = (short)f2bf(acc[16 + r]); v1[r] = (short)f2bf(acc[24 + r]); }
    *(short8*)(kT + row) = v0;  *(short8*)(kT + row + 8) = v1;
  } else {
    const int pbase = wu * 32 - 32;
#pragma unroll
    for (int r = 0; r < 32; ++r)
      v2s[(pbase + r) * 72 + lane] = f2bf(acc[r]);
  }
  __syncthreads();

  // coalesced v2 stores: 96 rows x 64 l, 8B per thread-chunk, padded pitch
#pragma unroll
  for (int i = 0; i < 6; ++i) {
    const int idx = tid + i * 256;                 // 0..1535
    const int p = idx >> 4, off = (idx & 15) * 4;
    const uint2 val = *(const uint2*)(v2s + p * 72 + off);
    *(uint2*)(v2w + ((size_t)(b * P_ + p)) * VP + l0 + off) = val;
  }
}

// ---------------------------------------------------------------------------
// k_attn: transposed flash attention, 32x32x16 bf16 MFMA, K = d = 16 exactly.
//   S^T = K Q^T ; P = exp2(S^T) (no max subtraction: logits bounded, softmax
//   shift-invariant) ; O^T = V^T P^T with P^T built in-register via one
//   half-wave shfl_xor(32) pair per 16-m chunk. No LDS in the main loop.
// V reads: 32 rows/instr at the PADDED pitch (8448 B = 256*33) -> the 32 lane
// addresses land on 32 DIFFERENT L2 channels (4096-pitch put them all on one).
// Block = 1024 thr = 16 waves = 4 q-groups (32 q-rows) x 4 m-slices (1024 m).
// ---------------------------------------------------------------------------
__global__ __launch_bounds__(1024, 4) void k_attn(
    const unsigned short* __restrict__ qT, const unsigned short* __restrict__ kT,
    const unsigned short* __restrict__ v2w, const float* __restrict__ b2,
    float* __restrict__ y)
{
  __shared__ float ldsO[P_ * 128];   // [p][l] 48 KB
  __shared__ float ldsL[128];

  const int b = blockIdx.y;
  const int l0 = blockIdx.x * 128;
  const int tid = threadIdx.x;
  const int w  = tid >> 6;
  const int qg = w & 3;          // q-group
  const int ms = w >> 2;         // m-slice
  const int lane = tid & 63;
  const int col = lane & 31;
  const int hh  = lane >> 5;     // half-wave

#pragma unroll
  for (int i = 0; i < 12; ++i) ldsO[tid + i * 1024] = 0.f;
  if (tid < 128) ldsL[tid] = 0.f;
  __syncthreads();

  // Q^T B-fragment: B[k=8*hh+j][n=col], row lq of qT
  const int lq = l0 + qg * 32 + col;
  const short8 qf = *(const short8*)(qT + ((size_t)(b * L_ + lq)) * D_ + hh * 8);

  float16v oacc[3];
#pragma unroll
  for (int pt = 0; pt < 3; ++pt)
#pragma unroll
    for (int r = 0; r < 16; ++r) oacc[pt][r] = 0.f;
  float lsum = 0.f;

  const unsigned short* kbase =
      kT + ((size_t)(b * L_ + ms * 1024 + col)) * D_ + hh * 8;
  const unsigned short* vbb = v2w + ((size_t)(b * P_ + col)) * VP;

  short8 kf_cur = *(const short8*)(kbase);

#pragma unroll 2
  for (int it = 0; it < 32; ++it) {
    // prefetch next K-frag (head of the S dependency chain)
    const int itn = (it + 1) & 31;                 // wrap: always valid
    const short8 kf_nxt = *(const short8*)(kbase + (size_t)itn * 32 * D_);

    // issue this iteration's V-frags now; exp chain below hides their latency
    const int mbase = ms * 1024 + it * 32;
    short8 vf[6];
#pragma unroll
    for (int mt = 0; mt < 2; ++mt)
#pragma unroll
      for (int pt = 0; pt < 3; ++pt)
        vf[mt * 3 + pt] = *(const short8*)(vbb + (size_t)pt * 32 * VP
                                           + (size_t)(mbase + mt * 16 + hh * 8));

    float16v zero;
#pragma unroll
    for (int r = 0; r < 16; ++r) zero[r] = 0.f;
    const float16v s = __builtin_amdgcn_mfma_f32_32x32x16_bf16(kf_cur, qf, zero, 0, 0, 0);

    // P = exp2(S^T); pack bf16 pairs
    unsigned dw[8];
#pragma unroll
    for (int g = 0; g < 8; ++g) {
      const float e0 = __builtin_amdgcn_exp2f(s[2 * g]);
      const float e1 = __builtin_amdgcn_exp2f(s[2 * g + 1]);
      lsum += e0 + e1;
      const unsigned u0 = __float_as_uint(e0) + 0x8000u;
      const unsigned u1 = __float_as_uint(e1) + 0x8000u;
      dw[g] = __builtin_amdgcn_perm(u1, u0, 0x07060302u);  // (bf(e1)<<16)|bf(e0)
    }

#pragma unroll
    for (int mt = 0; mt < 2; ++mt) {
      // build P^T B-frag for k = mt*16 + 8*hh + j via half-wave exchange
      const unsigned t0 = hh ? dw[4 * mt + 0] : dw[4 * mt + 2];
      const unsigned t1 = hh ? dw[4 * mt + 1] : dw[4 * mt + 3];
      const unsigned r0 = (unsigned)__shfl_xor((int)t0, 32);
      const unsigned r1 = (unsigned)__shfl_xor((int)t1, 32);
      union { int4 i; short8 s8; } pu;
      pu.i.x = hh ? (int)r0 : (int)dw[4 * mt + 0];
      pu.i.y = hh ? (int)r1 : (int)dw[4 * mt + 1];
      pu.i.z = hh ? (int)dw[4 * mt + 2] : (int)r0;
      pu.i.w = hh ? (int)dw[4 * mt + 3] : (int)r1;
      const short8 pf = pu.s8;
#pragma unroll
      for (int pt = 0; pt < 3; ++pt)
        oacc[pt] = __builtin_amdgcn_mfma_f32_32x32x16_bf16(vf[mt * 3 + pt], pf, oacc[pt], 0, 0, 0);
    }
    kf_cur = kf_nxt;
  }

  // combine partials across m-slices (and half-waves) in LDS
  atomicAdd(&ldsL[qg * 32 + col], lsum);
#pragma unroll
  for (int pt = 0; pt < 3; ++pt)
#pragma unroll
    for (int r = 0; r < 16; ++r) {
      const int p = (r & 3) + 8 * (r >> 2) + 4 * hh + 32 * pt;
      atomicAdd(&ldsO[p * 128 + qg * 32 + col], oacc[pt][r]);
    }
  __syncthreads();

  // y[b,p,l0+l] = O^T[p][l]/lsum[l] + b2[p]
#pragma unroll
  for (int i = 0; i < 12; ++i) {
    const int idx = tid + i * 1024;
    const int p = idx >> 7;
    const int l = idx & 127;
    y[((size_t)(b * P_ + p)) * L_ + l0 + l] = ldsO[idx] / ldsL[l] + b2[p];
  }
}

// ---------------------------------------------------------------------------
extern "C" void kernel_launch(void* const* d_in, const int* in_sizes, int n_in,
                              void* d_out, int out_size, void* d_ws, size_t ws_size,
                              hipStream_t stream) {
  (void)in_sizes; (void)n_in; (void)out_size; (void)ws_size;
  const float* x     = (const float*)d_in[0];
  const float* Wt    = (const float*)d_in[1];
  // d_in[2] = bt: unused — BatchNorm mean-subtraction cancels it exactly.
  const float* gamma = (const float*)d_in[3];
  const float* beta  = (const float*)d_in[4];
  const float* Wq    = (const float*)d_in[5];
  const float* bq    = (const float*)d_in[6];
  const float* Wk    = (const float*)d_in[7];
  const float* bk    = (const float*)d_in[8];
  const float* Wv    = (const float*)d_in[9];
  const float* bv    = (const float*)d_in[10];
  const float* W2    = (const float*)d_in[11];
  const float* b2    = (const float*)d_in[12];
  float* y = (float*)d_out;

  char* ws = (char*)d_ws;
  float* h       = (float*)(ws + OFF_H);
  float* psum    = (float*)(ws + OFF_PSUM);
  float* psumsq  = (float*)(ws + OFF_PSUMSQ);
  float* scale   = (float*)(ws + OFF_SCALE);
  float* shift   = (float*)(ws + OFF_SHIFT);
  float* wallT   = (float*)(ws + OFF_WALLT);
  float* ball    = (float*)(ws + OFF_BALL);
  unsigned short* qT  = (unsigned short*)(ws + OFF_QT);
  unsigned short* kT  = (unsigned short*)(ws + OFF_KT);
  unsigned short* v2w = (unsigned short*)(ws + OFF_V2);

  k_prep<<<128, 128, 0, stream>>>(Wq, bq, Wk, bk, Wv, bv, W2, wallT, ball);
  k_conv<<<dim3(4, 128), 256, 0, stream>>>(x, Wt, h, psum, psumsq);
  k_bn<<<1, 128, 0, stream>>>(psum, psumsq, gamma, beta, scale, shift);
  k_proj<<<dim3(64, 8), 256, 0, stream>>>(h, scale, shift, wallT, ball, qT, kT, v2w);
  k_attn<<<dim3(32, 8), 1024, 0, stream>>>(qT, kT, v2w, b2, y);
}

// Round 5
// 525.390 us; speedup vs baseline: 1.1048x; 1.0978x over previous
//
#include <hip/hip_runtime.h>

#define B_ 8
#define C_ 128
#define L_ 4096
#define P_ 96
#define D_ 16

typedef __attribute__((ext_vector_type(8))) short short8;
typedef __attribute__((ext_vector_type(16))) float float16v;

__device__ __forceinline__ unsigned short f2bf(float f) {
  unsigned int u = __float_as_uint(f);
  u += 0x7fff + ((u >> 16) & 1);          // round-to-nearest-even
  return (unsigned short)(u >> 16);
}

// ---------------------------------------------------------------------------
// Workspace layout (bytes)
// ---------------------------------------------------------------------------
constexpr size_t OFF_H      = 0;                      // h  [B][C][L] f32 : 16 MB
constexpr size_t OFF_PSUM   = 16777216;               // [C][4] f32
constexpr size_t OFF_PSUMSQ = OFF_PSUM + 8192;
constexpr size_t OFF_SCALE  = OFF_PSUMSQ + 8192;      // [C] f32
constexpr size_t OFF_SHIFT  = OFF_SCALE + 512;
constexpr size_t OFF_WALLT  = OFF_SHIFT + 512;        // WallT [c][r] f32 64 KB
constexpr size_t OFF_BALL   = OFF_WALLT + 65536;      // [128] f32
constexpr size_t OFF_QT     = OFF_BALL + 512;         // [B][L][16] bf16 (q pre-scaled by log2e)
constexpr size_t OFF_KT     = OFF_QT + 1048576;       // [B][L][16] bf16
constexpr size_t OFF_V2     = OFF_KT + 1048576;       // v2t [B][L/16][96][16] bf16 : 6 MB
                                                      // = MFMA A-frag order: one vf load
                                                      // is 1 KB CONTIGUOUS (was a 32-line gather)

// ---------------------------------------------------------------------------
// k_prep: rows 0..15 = Wq, 16..31 = Wk, 32..127 = Wv2 = W2 @ Wv.
// Stored transposed wallT[c*128+r]. ball = {bq, bk, W2@bv}. bt is annihilated
// by BatchNorm shift-invariance and never read.
// ---------------------------------------------------------------------------
__global__ __launch_bounds__(128) void k_prep(
    const float* __restrict__ Wq, const float* __restrict__ bq,
    const float* __restrict__ Wk, const float* __restrict__ bk,
    const float* __restrict__ Wv, const float* __restrict__ bv,
    const float* __restrict__ W2,
    float* __restrict__ wallT, float* __restrict__ ball)
{
  const int r = blockIdx.x;
  const int c = threadIdx.x;
  float wv;
  if (r < 16) {
    wv = Wq[r * C_ + c];
  } else if (r < 32) {
    wv = Wk[(r - 16) * C_ + c];
  } else {
    const int p = r - 32;
    float s = 0.f;
#pragma unroll 8
    for (int o = 0; o < C_; ++o) s += W2[p * C_ + o] * Wv[o * C_ + c];
    wv = s;
  }
  wallT[c * C_ + r] = wv;
  if (c == 0) {
    float bb;
    if (r < 16)      bb = bq[r];
    else if (r < 32) bb = bk[r - 16];
    else {
      const int p = r - 32;
      float s = 0.f;
#pragma unroll 8
      for (int o = 0; o < C_; ++o) s += W2[p * C_ + o] * bv[o];
      bb = s;
    }
    ball[r] = bb;
  }
}

// ---------------------------------------------------------------------------
// k_conv: h[b,o,l] = sum_i x[b,i] * Wt[i,o,l].
// Double-buffered float4 loads (8 in flight); per-block phase rotation of the
// i-order decorrelates the 2 MB stride across blocks. Deterministic BN partials.
// ---------------------------------------------------------------------------
__global__ __launch_bounds__(256) void k_conv(
    const float* __restrict__ x, const float* __restrict__ Wt,
    float* __restrict__ h, float* __restrict__ psum, float* __restrict__ psumsq)
{
  __shared__ float4 xs4[256];                 // [b][i4] = b*32+i4
  __shared__ float rs1[4], rs2[4];
  const int tid = threadIdx.x;
  const int o = blockIdx.y;
  const int l = blockIdx.x * 1024 + tid * 4;

  xs4[tid] = ((const float4*)x)[tid];        // 1024 floats exactly
  __syncthreads();

  float4 acc[8];
#pragma unroll
  for (int bb = 0; bb < 8; ++bb) acc[bb] = (float4){0.f, 0.f, 0.f, 0.f};

  const float* wp = Wt + (size_t)o * L_ + l;
  const size_t stride = (size_t)C_ * L_;
  const int phase = (blockIdx.y + blockIdx.x * 8) & 31;

  float4 wbuf[2][4];
#pragma unroll
  for (int q = 0; q < 4; ++q)
    wbuf[0][q] = *(const float4*)(wp + (size_t)(phase * 4 + q) * stride);

#pragma unroll 2
  for (int g = 0; g < 32; ++g) {
    const int cur = g & 1, nb = cur ^ 1;
    const int in4 = ((phase + g + 1) & 31) * 4;   // wraps: always valid
#pragma unroll
    for (int q = 0; q < 4; ++q)
      wbuf[nb][q] = *(const float4*)(wp + (size_t)(in4 + q) * stride);

    const int ic = (phase + g) & 31;
#pragma unroll
    for (int bb = 0; bb < 8; ++bb) {
      const float4 xb = xs4[bb * 32 + ic];   // wave-uniform addr: broadcast
      acc[bb].x += xb.x * wbuf[cur][0].x + xb.y * wbuf[cur][1].x + xb.z * wbuf[cur][2].x + xb.w * wbuf[cur][3].x;
      acc[bb].y += xb.x * wbuf[cur][0].y + xb.y * wbuf[cur][1].y + xb.z * wbuf[cur][2].y + xb.w * wbuf[cur][3].y;
      acc[bb].z += xb.x * wbuf[cur][0].z + xb.y * wbuf[cur][1].z + xb.z * wbuf[cur][2].z + xb.w * wbuf[cur][3].z;
      acc[bb].w += xb.x * wbuf[cur][0].w + xb.y * wbuf[cur][1].w + xb.z * wbuf[cur][2].w + xb.w * wbuf[cur][3].w;
    }
  }
  float s1 = 0.f, s2 = 0.f;
#pragma unroll
  for (int bb = 0; bb < 8; ++bb) {
    *(float4*)(h + ((size_t)(bb * C_ + o)) * L_ + l) = acc[bb];
    s1 += acc[bb].x + acc[bb].y + acc[bb].z + acc[bb].w;
    s2 += acc[bb].x * acc[bb].x + acc[bb].y * acc[bb].y
        + acc[bb].z * acc[bb].z + acc[bb].w * acc[bb].w;
  }
  for (int off = 1; off < 64; off <<= 1) {
    s1 += __shfl_xor(s1, off);
    s2 += __shfl_xor(s2, off);
  }
  if ((tid & 63) == 0) { rs1[tid >> 6] = s1; rs2[tid >> 6] = s2; }
  __syncthreads();
  if (tid == 0) {
    psum[o * 4 + blockIdx.x]   = rs1[0] + rs1[1] + rs1[2] + rs1[3];
    psumsq[o * 4 + blockIdx.x] = rs2[0] + rs2[1] + rs2[2] + rs2[3];
  }
}

// ---------------------------------------------------------------------------
// k_bn: finalize per-channel scale/shift.
// ---------------------------------------------------------------------------
__global__ __launch_bounds__(128) void k_bn(
    const float* __restrict__ psum, const float* __restrict__ psumsq,
    const float* __restrict__ gamma, const float* __restrict__ beta,
    float* __restrict__ scale, float* __restrict__ shift)
{
  const int c = threadIdx.x;
  float s1 = 0.f, s2 = 0.f;
  for (int t = 0; t < 4; ++t) { s1 += psum[c * 4 + t]; s2 += psumsq[c * 4 + t]; }
  const float inv = 1.f / 32768.f;
  const float mean = s1 * inv;
  const float var  = s2 * inv - mean * mean;
  const float sc   = rsqrtf(var + 1e-5f) * gamma[c];
  scale[c] = sc;
  shift[c] = beta[c] - mean * sc;
}

// ---------------------------------------------------------------------------
// k_proj: [q;k;v2] = Wall @ relu(bn(h)) + ball, bf16 out.
// h tile staged once into LDS (bn+relu applied); v2 stores bounce through LDS
// and land in the m-tiled layout v2t[b][m/16][p][m%16] (MFMA A-frag order),
// still as perfectly-coalesced consecutive 8B stores.
// q rows pre-scaled by log2e so attention uses raw v_exp_f32 (exp2).
// ---------------------------------------------------------------------------
__global__ __launch_bounds__(256) void k_proj(
    const float* __restrict__ h, const float* __restrict__ scale,
    const float* __restrict__ shift, const float* __restrict__ wallT,
    const float* __restrict__ ball,
    unsigned short* __restrict__ qT, unsigned short* __restrict__ kT,
    unsigned short* __restrict__ v2t)
{
  __shared__ __align__(16) char sm[128 * 68 * 4];     // 34 KB
  float* hn = (float*)sm;                             // [c][68] f32, 64 used
  unsigned short* v2s = (unsigned short*)sm;          // reused: [p][72] bf16

  const int b = blockIdx.y;
  const int l0 = blockIdx.x * 64;
  const int tid = threadIdx.x;

  // stage + bn + relu: 128c x 64l tile
#pragma unroll
  for (int i = 0; i < 8; ++i) {
    const int idx = tid + i * 256;
    const int c = idx >> 4, lq = (idx & 15) * 4;
    const float4 hv = *(const float4*)(h + ((size_t)(b * C_ + c)) * L_ + l0 + lq);
    const float sc = scale[c], sh = shift[c];
    float4 r;
    r.x = fmaxf(hv.x * sc + sh, 0.f);
    r.y = fmaxf(hv.y * sc + sh, 0.f);
    r.z = fmaxf(hv.z * sc + sh, 0.f);
    r.w = fmaxf(hv.w * sc + sh, 0.f);
    *(float4*)(hn + c * 68 + lq) = r;
  }
  __syncthreads();

  const int wu = __builtin_amdgcn_readfirstlane(tid) >> 6;  // wave id, uniform
  const int lane = tid & 63;
  const int l = l0 + lane;

  float acc[32];
#pragma unroll
  for (int r = 0; r < 32; ++r) acc[r] = ball[wu * 32 + r];

#pragma unroll 4
  for (int c = 0; c < C_; ++c) {
    const float hv = hn[c * 68 + lane];
    const float* wrow = wallT + c * C_ + wu * 32;   // wave-uniform: s_load
#pragma unroll
    for (int r = 0; r < 32; ++r) acc[r] += wrow[r] * hv;
  }
  __syncthreads();   // all waves done reading hn before LDS reuse

  if (wu == 0) {
    const size_t row = (size_t)(b * L_ + l) * D_;
    short8 v0, v1;
#pragma unroll
    for (int r = 0; r < 8; ++r) {
      v0[r] = (short)f2bf(acc[r] * 1.44269504f);        // q * log2(e)
      v1[r] = (short)f2bf(acc[8 + r] * 1.44269504f);
    }
    *(short8*)(qT + row) = v0;  *(short8*)(qT + row + 8) = v1;
#pragma unroll
    for (int r = 0; r < 8; ++r) { v0[r] = (short)f2bf(acc[16 + r]); v1[r] = (short)f2bf(acc[24 + r]); }
    *(short8*)(kT + row) = v0;  *(short8*)(kT + row + 8) = v1;
  } else {
    const int pbase = wu * 32 - 32;
#pragma unroll
    for (int r = 0; r < 32; ++r)
      v2s[(pbase + r) * 72 + lane] = f2bf(acc[r]);
  }
  __syncthreads();

  // v2 stores, m-tiled: uint2 j in [0,1536): mo4=j&3, p=(j>>2)%96, mtl=(j>>2)/96
  // dst linear in j -> consecutive 8B stores, fully coalesced.
#pragma unroll
  for (int i = 0; i < 6; ++i) {
    const int j = tid + i * 256;
    const int mo4 = j & 3;
    const int jp = j >> 2;
    const int p = jp % 96;
    const int mtl = jp / 96;                       // 0..3
    const uint2 val = *(const uint2*)(v2s + p * 72 + mtl * 16 + mo4 * 4);
    *(uint2*)(v2t + ((size_t)((b * (L_ / 16) + blockIdx.x * 4 + mtl)) * P_ + p) * 16
              + mo4 * 4) = val;
  }
}

// ---------------------------------------------------------------------------
// k_attn: transposed flash attention, 32x32x16 bf16 MFMA, K = d = 16 exactly.
//   S^T = K Q^T ; P = exp2(S^T) (no max subtraction: logits bounded, softmax
//   shift-invariant) ; O^T = V^T P^T with P^T built in-register via one
//   half-wave shfl_xor(32) pair per 16-m chunk. No LDS in the main loop.
// V reads now hit the m-tiled layout v2t[b][m/16][p][m%16]: one vf fragment
// load = lanes (col,hh) reading (pt*32+col)*32B + hh*16B = 1 KB CONTIGUOUS
// (previously a 32-cache-line gather that serialized the texture pipe).
// Block = 1024 thr = 16 waves = 4 q-groups (32 q-rows) x 4 m-slices (1024 m).
// ---------------------------------------------------------------------------
__global__ __launch_bounds__(1024, 4) void k_attn(
    const unsigned short* __restrict__ qT, const unsigned short* __restrict__ kT,
    const unsigned short* __restrict__ v2t, const float* __restrict__ b2,
    float* __restrict__ y)
{
  __shared__ float ldsO[P_ * 128];   // [p][l] 48 KB
  __shared__ float ldsL[128];

  const int b = blockIdx.y;
  const int l0 = blockIdx.x * 128;
  const int tid = threadIdx.x;
  const int w  = tid >> 6;
  const int qg = w & 3;          // q-group
  const int ms = w >> 2;         // m-slice
  const int lane = tid & 63;
  const int col = lane & 31;
  const int hh  = lane >> 5;     // half-wave

#pragma unroll
  for (int i = 0; i < 12; ++i) ldsO[tid + i * 1024] = 0.f;
  if (tid < 128) ldsL[tid] = 0.f;
  __syncthreads();

  // Q^T B-fragment: B[k=8*hh+j][n=col], row lq of qT
  const int lq = l0 + qg * 32 + col;
  const short8 qf = *(const short8*)(qT + ((size_t)(b * L_ + lq)) * D_ + hh * 8);

  float16v oacc[3];
#pragma unroll
  for (int pt = 0; pt < 3; ++pt)
#pragma unroll
    for (int r = 0; r < 16; ++r) oacc[pt][r] = 0.f;
  float lsum = 0.f;

  const unsigned short* kbase =
      kT + ((size_t)(b * L_ + ms * 1024 + col)) * D_ + hh * 8;
  // v2t base for this batch; fragment (mt16, pt) at ((mt16)*96 + pt*32+col)*16 + hh*8
  const unsigned short* vtb = v2t + (size_t)b * (L_ / 16) * P_ * 16
                              + (size_t)col * 16 + hh * 8;

  short8 kf_cur = *(const short8*)(kbase);

#pragma unroll 2
  for (int it = 0; it < 32; ++it) {
    // prefetch next K-frag (head of the S dependency chain)
    const int itn = (it + 1) & 31;                 // wrap: always valid
    const short8 kf_nxt = *(const short8*)(kbase + (size_t)itn * 32 * D_);

    // issue this iteration's V-frags now; exp chain below hides their latency
    const int mt16 = ms * 64 + it * 2;             // m-tile index (16 m per tile)
    short8 vf[6];
#pragma unroll
    for (int mt = 0; mt < 2; ++mt)
#pragma unroll
      for (int pt = 0; pt < 3; ++pt)
        vf[mt * 3 + pt] = *(const short8*)(vtb
            + ((size_t)(mt16 + mt) * P_ + pt * 32) * 16);

    float16v zero;
#pragma unroll
    for (int r = 0; r < 16; ++r) zero[r] = 0.f;
    const float16v s = __builtin_amdgcn_mfma_f32_32x32x16_bf16(kf_cur, qf, zero, 0, 0, 0);

    // P = exp2(S^T); pack bf16 pairs
    unsigned dw[8];
#pragma unroll
    for (int g = 0; g < 8; ++g) {
      const float e0 = __builtin_amdgcn_exp2f(s[2 * g]);
      const float e1 = __builtin_amdgcn_exp2f(s[2 * g + 1]);
      lsum += e0 + e1;
      const unsigned u0 = __float_as_uint(e0) + 0x8000u;
      const unsigned u1 = __float_as_uint(e1) + 0x8000u;
      dw[g] = __builtin_amdgcn_perm(u1, u0, 0x07060302u);  // (bf(e1)<<16)|bf(e0)
    }

#pragma unroll
    for (int mt = 0; mt < 2; ++mt) {
      // build P^T B-frag for k = mt*16 + 8*hh + j via half-wave exchange
      const unsigned t0 = hh ? dw[4 * mt + 0] : dw[4 * mt + 2];
      const unsigned t1 = hh ? dw[4 * mt + 1] : dw[4 * mt + 3];
      const unsigned r0 = (unsigned)__shfl_xor((int)t0, 32);
      const unsigned r1 = (unsigned)__shfl_xor((int)t1, 32);
      union { int4 i; short8 s8; } pu;
      pu.i.x = hh ? (int)r0 : (int)dw[4 * mt + 0];
      pu.i.y = hh ? (int)r1 : (int)dw[4 * mt + 1];
      pu.i.z = hh ? (int)dw[4 * mt + 2] : (int)r0;
      pu.i.w = hh ? (int)dw[4 * mt + 3] : (int)r1;
      const short8 pf = pu.s8;
#pragma unroll
      for (int pt = 0; pt < 3; ++pt)
        oacc[pt] = __builtin_amdgcn_mfma_f32_32x32x16_bf16(vf[mt * 3 + pt], pf, oacc[pt], 0, 0, 0);
    }
    kf_cur = kf_nxt;
  }

  // combine partials across m-slices (and half-waves) in LDS
  atomicAdd(&ldsL[qg * 32 + col], lsum);
#pragma unroll
  for (int pt = 0; pt < 3; ++pt)
#pragma unroll
    for (int r = 0; r < 16; ++r) {
      const int p = (r & 3) + 8 * (r >> 2) + 4 * hh + 32 * pt;
      atomicAdd(&ldsO[p * 128 + qg * 32 + col], oacc[pt][r]);
    }
  __syncthreads();

  // y[b,p,l0+l] = O^T[p][l]/lsum[l] + b2[p]
#pragma unroll
  for (int i = 0; i < 12; ++i) {
    const int idx = tid + i * 1024;
    const int p = idx >> 7;
    const int l = idx & 127;
    y[((size_t)(b * P_ + p)) * L_ + l0 + l] = ldsO[idx] / ldsL[l] + b2[p];
  }
}

// ---------------------------------------------------------------------------
extern "C" void kernel_launch(void* const* d_in, const int* in_sizes, int n_in,
                              void* d_out, int out_size, void* d_ws, size_t ws_size,
                              hipStream_t stream) {
  (void)in_sizes; (void)n_in; (void)out_size; (void)ws_size;
  const float* x     = (const float*)d_in[0];
  const float* Wt    = (const float*)d_in[1];
  // d_in[2] = bt: unused — BatchNorm mean-subtraction cancels it exactly.
  const float* gamma = (const float*)d_in[3];
  const float* beta  = (const float*)d_in[4];
  const float* Wq    = (const float*)d_in[5];
  const float* bq    = (const float*)d_in[6];
  const float* Wk    = (const float*)d_in[7];
  const float* bk    = (const float*)d_in[8];
  const float* Wv    = (const float*)d_in[9];
  const float* bv    = (const float*)d_in[10];
  const float* W2    = (const float*)d_in[11];
  const float* b2    = (const float*)d_in[12];
  float* y = (float*)d_out;

  char* ws = (char*)d_ws;
  float* h       = (float*)(ws + OFF_H);
  float* psum    = (float*)(ws + OFF_PSUM);
  float* psumsq  = (float*)(ws + OFF_PSUMSQ);
  float* scale   = (float*)(ws + OFF_SCALE);
  float* shift   = (float*)(ws + OFF_SHIFT);
  float* wallT   = (float*)(ws + OFF_WALLT);
  float* ball    = (float*)(ws + OFF_BALL);
  unsigned short* qT  = (unsigned short*)(ws + OFF_QT);
  unsigned short* kT  = (unsigned short*)(ws + OFF_KT);
  unsigned short* v2t = (unsigned short*)(ws + OFF_V2);

  k_prep<<<128, 128, 0, stream>>>(Wq, bq, Wk, bk, Wv, bv, W2, wallT, ball);
  k_conv<<<dim3(4, 128), 256, 0, stream>>>(x, Wt, h, psum, psumsq);
  k_bn<<<1, 128, 0, stream>>>(psum, psumsq, gamma, beta, scale, shift);
  k_proj<<<dim3(64, 8), 256, 0, stream>>>(h, scale, shift, wallT, ball, qT, kT, v2t);
  k_attn<<<dim3(32, 8), 1024, 0, stream>>>(qT, kT, v2t, b2, y);
}